// Round 11
// baseline (2598.913 us; speedup 1.0000x reference)
//
#include <hip/hip_runtime.h>
#include <stdint.h>

typedef unsigned short u16;
typedef __bf16 bf16x8 __attribute__((ext_vector_type(8)));
typedef u16   u16x8  __attribute__((ext_vector_type(8)));
typedef float f32x4  __attribute__((ext_vector_type(4)));
typedef float f32x16 __attribute__((ext_vector_type(16)));

#define AS1(p) (const __attribute__((address_space(1))) void*)(p)
#define AS3(p) (__attribute__((address_space(3))) void*)(p)

__device__ __forceinline__ u16 f2b(float f){
  uint32_t u = __builtin_bit_cast(uint32_t, f);
  u = (u + 0x7FFFu + ((u >> 16) & 1u)) >> 16;
  return (u16)u;
}
__device__ __forceinline__ float fexp2(float x){
#if __has_builtin(__builtin_amdgcn_exp2f)
  return __builtin_amdgcn_exp2f(x);
#else
  return exp2f(x);
#endif
}

// ---------------- embedding
__global__ __launch_bounds__(256) void embed_k(const int* __restrict__ tokens,
                                               const float* __restrict__ te,
                                               const float* __restrict__ pe,
                                               float* __restrict__ x){
  const int n = blockIdx.x, tid = threadIdx.x;
  const int tok = tokens[n];
  float4 a = *(const float4*)&te[(size_t)tok * 1024 + tid * 4];
  const float4 p = *(const float4*)&pe[(size_t)(n & 2047) * 1024 + tid * 4];
  a.x += p.x; a.y += p.y; a.z += p.z; a.w += p.w;
  *(float4*)&x[(size_t)n * 1024 + tid * 4] = a;
}

// ---------------- LayerNorm (D=1024), f32 in -> bf16 out
__global__ __launch_bounds__(256) void ln_k(const float* __restrict__ x,
                                            const float* __restrict__ g,
                                            const float* __restrict__ b,
                                            u16* __restrict__ h){
  const int row = blockIdx.x, tid = threadIdx.x;
  const float4 v = *(const float4*)&x[(size_t)row * 1024 + tid * 4];
  float s = v.x + v.y + v.z + v.w;
  float q = v.x*v.x + v.y*v.y + v.z*v.z + v.w*v.w;
#pragma unroll
  for (int m = 32; m; m >>= 1){ s += __shfl_xor(s, m); q += __shfl_xor(q, m); }
  __shared__ float ss[4], qq[4];
  if ((tid & 63) == 0){ ss[tid >> 6] = s; qq[tid >> 6] = q; }
  __syncthreads();
  s = ss[0] + ss[1] + ss[2] + ss[3];
  q = qq[0] + qq[1] + qq[2] + qq[3];
  const float mean = s * (1.f/1024.f);
  const float var  = q * (1.f/1024.f) - mean*mean;
  const float rstd = rsqrtf(var + 1e-5f);
  const float4 gv = *(const float4*)&g[tid*4];
  const float4 bv = *(const float4*)&b[tid*4];
  ushort4 o;
  o.x = f2b((v.x-mean)*rstd*gv.x + bv.x);
  o.y = f2b((v.y-mean)*rstd*gv.y + bv.y);
  o.z = f2b((v.z-mean)*rstd*gv.z + bv.z);
  o.w = f2b((v.w-mean)*rstd*gv.w + bv.w);
  *(ushort4*)&h[(size_t)row * 1024 + tid * 4] = o;
}

// ---------------- shared transpose-convert tile body
__device__ __forceinline__ void conv_tile(const float* __restrict__ src,
                                          u16* __restrict__ dst,
                                          int R, int C, int bx, int by,
                                          u16 (*t)[72], int tid){
  const int r0 = by * 64, c0 = bx * 64;
  const int row = tid >> 4, col4 = tid & 15;
#pragma unroll
  for (int p = 0; p < 4; ++p){
    const int r = row + p * 16;
    const float4 v = *(const float4*)&src[(size_t)(r0 + r) * C + c0 + col4 * 4];
    t[r][col4*4+0] = f2b(v.x); t[r][col4*4+1] = f2b(v.y);
    t[r][col4*4+2] = f2b(v.z); t[r][col4*4+3] = f2b(v.w);
  }
  __syncthreads();
#pragma unroll
  for (int p = 0; p < 4; ++p){
    const int rr = row + p * 16;
    ushort4 w;
    w.x = t[col4*4+0][rr]; w.y = t[col4*4+1][rr];
    w.z = t[col4*4+2][rr]; w.w = t[col4*4+3][rr];
    *(ushort4*)&dst[(size_t)(c0 + rr) * R + r0 + col4 * 4] = w;
  }
}

__global__ __launch_bounds__(256) void conv_t(const float* __restrict__ src,
                                              u16* __restrict__ dst,
                                              int R, int C){
  __shared__ u16 t[64][72];
  conv_tile(src, dst, R, C, blockIdx.x, blockIdx.y, t, threadIdx.x);
}

__global__ __launch_bounds__(256) void conv6_k(const float* __restrict__ Wq,
                                               const float* __restrict__ Wk,
                                               const float* __restrict__ Wv,
                                               const float* __restrict__ Wo,
                                               const float* __restrict__ W1,
                                               const float* __restrict__ W2,
                                               u16* __restrict__ qkvT,
                                               u16* __restrict__ woT,
                                               u16* __restrict__ w1T,
                                               u16* __restrict__ w2T){
  __shared__ u16 t[64][72];
  const int id = blockIdx.x;
  const float* src; u16* dst; int R, C, bx, by;
  if (id < 1024){
    R = 1024; C = 1024;
    const int m = id >> 8, tt = id & 255; bx = tt & 15; by = tt >> 4;
    if (m == 0){ src = Wq; dst = qkvT; }
    else if (m == 1){ src = Wk; dst = qkvT + 1048576; }
    else if (m == 2){ src = Wv; dst = qkvT + 2097152; }
    else { src = Wo; dst = woT; }
  } else if (id < 2048){
    const int tt = id - 1024; R = 1024; C = 4096; bx = tt & 63; by = tt >> 6;
    src = W1; dst = w1T;
  } else {
    const int tt = id - 2048; R = 4096; C = 1024; bx = tt & 15; by = tt >> 4;
    src = W2; dst = w2T;
  }
  conv_tile(src, dst, R, C, bx, by, t, threadIdx.x);
}

// ---------------- 128x128 bf16 MFMA GEMM (2-barrier structure, 32x32x16 MFMA)
// LDS layout: chunk-major within each 8-row group — logical (row R, 16B-chunk
// cx in [0,8)) lives at elem (R>>3)*512 + cx*64 + (R&7)*8. Per MFMA read
// (32 rows x chunks {2s,2s+1}) each 128B unit-row is covered fully (8 distinct
// slots) -> conflict-free per the round-7/10 A/B coverage criterion.
// Stager: lane writes 16B at lane*16 in its wave region; source row = base +
// (lane&7), chunk = lane>>3 (same bytes as before -> FETCH unchanged).
template<int EPI>
__global__ __launch_bounds__(256) void gemm_bt(const u16* __restrict__ A,
                                               const u16* __restrict__ BT,
                                               void* __restrict__ Cout,
                                               const float* __restrict__ bias,
                                               int M, int N, int K){
  __shared__ __attribute__((aligned(16))) u16 As[128 * 64];
  __shared__ __attribute__((aligned(16))) u16 Bs[128 * 64];
  const int tid = threadIdx.x;
  const int lane = tid & 63, wave = tid >> 6;
  const int m0 = blockIdx.x * 128, n0 = blockIdx.y * 128;
  const int wm = wave >> 1, wn = wave & 1;
  const int l31 = lane & 31, l5 = lane >> 5;

  const u16* Ag = A  + (size_t)(m0 + wave*8 + (lane & 7)) * K + (lane >> 3) * 8;
  const u16* Bg = BT + (size_t)(n0 + wave*8 + (lane & 7)) * K + (lane >> 3) * 8;
  char* AsB = (char*)As + wave * 1024;
  char* BsB = (char*)Bs + wave * 1024;

  // logical (row R, chunk cx) -> physical elem
#define BOFF(R, cx) ((((R) >> 3) * 512) + (cx) * 64 + ((R) & 7) * 8)

  f32x16 acc[2][2] = {};

  for (int k0 = 0; k0 < K; k0 += 64){
    __syncthreads();
#pragma unroll
    for (int c = 0; c < 4; ++c){
      __builtin_amdgcn_global_load_lds(AS1(Ag + (size_t)(c*32)*K + k0), AS3(AsB + c*4096), 16, 0, 0);
      __builtin_amdgcn_global_load_lds(AS1(Bg + (size_t)(c*32)*K + k0), AS3(BsB + c*4096), 16, 0, 0);
    }
    __syncthreads();
#pragma unroll
    for (int s = 0; s < 4; ++s){
      const int cx = s*2 + l5;
      const bf16x8 af0 = *(const bf16x8*)&As[BOFF(wm*64 +      l31, cx)];
      const bf16x8 af1 = *(const bf16x8*)&As[BOFF(wm*64 + 32 + l31, cx)];
      const bf16x8 bf0 = *(const bf16x8*)&Bs[BOFF(wn*64 +      l31, cx)];
      const bf16x8 bf1 = *(const bf16x8*)&Bs[BOFF(wn*64 + 32 + l31, cx)];
      acc[0][0] = __builtin_amdgcn_mfma_f32_32x32x16_bf16(af0, bf0, acc[0][0], 0, 0, 0);
      acc[0][1] = __builtin_amdgcn_mfma_f32_32x32x16_bf16(af0, bf1, acc[0][1], 0, 0, 0);
      acc[1][0] = __builtin_amdgcn_mfma_f32_32x32x16_bf16(af1, bf0, acc[1][0], 0, 0, 0);
      acc[1][1] = __builtin_amdgcn_mfma_f32_32x32x16_bf16(af1, bf1, acc[1][1], 0, 0, 0);
    }
  }
#undef BOFF

#pragma unroll
  for (int mi = 0; mi < 2; ++mi){
#pragma unroll
    for (int ni = 0; ni < 2; ++ni){
      const f32x16 a = acc[mi][ni];
      const int c = n0 + wn*64 + ni*32 + l31;
      const float bb = (EPI == 1) ? (bias ? bias[c] : 0.f) : (EPI == 2 ? bias[c] : 0.f);
#pragma unroll
      for (int reg = 0; reg < 16; ++reg){
        const int r = m0 + wm*64 + mi*32 + (reg & 3) + 8*(reg >> 2) + 4*l5;
        if constexpr (EPI == 0){
          ((u16*)Cout)[(size_t)r*N + c] = f2b(a[reg]);
        } else if constexpr (EPI == 1){
          ((float*)Cout)[(size_t)r*N + c] += a[reg] + bb;
        } else if constexpr (EPI == 2){
          const float xv = a[reg] + bb;
          ((u16*)Cout)[(size_t)r*N + c] = f2b(0.5f * xv * (1.f + erff(xv * 0.70710678118654752f)));
        } else {
          ((float*)Cout)[(size_t)r*N + c] = a[reg];
        }
      }
    }
  }
}

// ---------------- 256x256 tile, BK=32, 3-slot ring, counted-vmcnt, 4 phases/tile
// 32x32x16 MFMA. LDS mapping (wave region = 16 rows x 4 chunks of 16B):
//   unit u = (rho&1)*2 + (cx&1) + 4*(cx>>1), slot = rho>>1  (rho = row&15)
// Per MFMA read (32 rows, cx in {2s,2s+1}): 4 unit-rows per region covered
// FULLY (8 distinct slots) -> conflict-free per the coverage criterion.
// Stager inverse: rloc = (lane&7)*2 + ((lane>>4)&1),
//                 cx   = ((lane>>5)&1)*2 + ((lane>>3)&1)   (bijective).
template<int EPI>
__global__ __launch_bounds__(512) void gemm_bt2(const u16* __restrict__ A,
                                                const u16* __restrict__ BT,
                                                void* __restrict__ Cout,
                                                const float* __restrict__ bias,
                                                int M, int N, int K){
  __shared__ __attribute__((aligned(16))) u16 Ls[3][2][256*32];  // 96 KiB
  const int tid = threadIdx.x;
  const int lane = tid & 63, wave = tid >> 6;
  const int m0 = blockIdx.x * 256, n0 = blockIdx.y * 256;
  const int wm = wave >> 2, wn = wave & 3;
  const int l31 = lane & 31, l5 = lane >> 5;

  // write-side inverse swizzle: this lane's logical (row-in-region, chunk)
  const int rloc = (lane & 7)*2 + ((lane >> 4) & 1);
  const int xl   = (((lane >> 5) & 1)*2 + ((lane >> 3) & 1)) * 8;

  const u16* Asrc = A  + (size_t)(m0 + wave*16 + rloc) * K + xl;
  const u16* Bsrc = BT + (size_t)(n0 + wave*16 + rloc) * K + xl;
  char* lds0 = (char*)&Ls[0][0][0];
  const int wb = wave * 1024;

  // logical (row r, 16B-chunk x in [0,4)) -> physical elem
#define LOFF2(r, x) ((((r) >> 4) * 512) + ((((r)&1)*2 + ((x)&1) + (((x)>>1)<<2)) * 64) + ((((r)&15) >> 1) * 8))

#define STG(sb, k0, L) do{ \
    __builtin_amdgcn_global_load_lds(AS1(Asrc + (size_t)((L)*128)*K + (size_t)(k0)), \
        AS3(lds0 + (sb)*32768 +         (L)*8192 + wb), 16, 0, 0); \
    __builtin_amdgcn_global_load_lds(AS1(Bsrc + (size_t)((L)*128)*K + (size_t)(k0)), \
        AS3(lds0 + (sb)*32768 + 16384 + (L)*8192 + wb), 16, 0, 0); \
  }while(0)

#define MM2(mi, a0, a1) do{ \
    acc[mi][0] = __builtin_amdgcn_mfma_f32_32x32x16_bf16((a0), bfv[0][0], acc[mi][0], 0, 0, 0); \
    acc[mi][1] = __builtin_amdgcn_mfma_f32_32x32x16_bf16((a0), bfv[1][0], acc[mi][1], 0, 0, 0); \
    acc[mi][0] = __builtin_amdgcn_mfma_f32_32x32x16_bf16((a1), bfv[0][1], acc[mi][0], 0, 0, 0); \
    acc[mi][1] = __builtin_amdgcn_mfma_f32_32x32x16_bf16((a1), bfv[1][1], acc[mi][1], 0, 0, 0); \
  }while(0)

  f32x16 acc[4][2] = {};
  const int nt = K >> 5;

  // prologue: tiles 0,1 -> slots 0,1; wait tile 0 (tile 1 stays in flight)
  STG(0, 0, 0);  STG(0, 0, 1);
  STG(1, 32, 0); STG(1, 32, 1);
  asm volatile("s_waitcnt vmcnt(4)" ::: "memory");
  __builtin_amdgcn_s_barrier();

  int buf = 0;
  for (int t = 0; t < nt; ++t){
    const u16* LA = &Ls[buf][0][0];
    const u16* LB = &Ls[buf][1][0];
    int sb = buf + 2; if (sb >= 3) sb -= 3;
    const int kn = (t + 2) << 5;
    const bool st = (t + 2) < nt;

    bf16x8 bfv[2][2], a0, a1;
    // ---- phase 0: all B frags + A(mi=0) ; stage half 0 of tile t+2 ----
#pragma unroll
    for (int ni = 0; ni < 2; ++ni)
#pragma unroll
      for (int s = 0; s < 2; ++s)
        bfv[ni][s] = *(const bf16x8*)&LB[LOFF2(wn*64 + ni*32 + l31, s*2 + l5)];
    a0 = *(const bf16x8*)&LA[LOFF2(wm*128 + 0*32 + l31, 0 + l5)];
    a1 = *(const bf16x8*)&LA[LOFF2(wm*128 + 0*32 + l31, 2 + l5)];
    if (st) STG(sb, kn, 0);
    __builtin_amdgcn_s_barrier();
    __builtin_amdgcn_s_setprio(1);
    MM2(0, a0, a1);
    __builtin_amdgcn_s_setprio(0);

    // ---- phase 1: A(mi=1) ----
    a0 = *(const bf16x8*)&LA[LOFF2(wm*128 + 1*32 + l31, 0 + l5)];
    a1 = *(const bf16x8*)&LA[LOFF2(wm*128 + 1*32 + l31, 2 + l5)];
    __builtin_amdgcn_s_barrier();
    __builtin_amdgcn_s_setprio(1);
    MM2(1, a0, a1);
    __builtin_amdgcn_s_setprio(0);

    // ---- phase 2: A(mi=2) ; stage half 1 ----
    a0 = *(const bf16x8*)&LA[LOFF2(wm*128 + 2*32 + l31, 0 + l5)];
    a1 = *(const bf16x8*)&LA[LOFF2(wm*128 + 2*32 + l31, 2 + l5)];
    if (st) STG(sb, kn, 1);
    __builtin_amdgcn_s_barrier();
    __builtin_amdgcn_s_setprio(1);
    MM2(2, a0, a1);
    __builtin_amdgcn_s_setprio(0);

    // ---- phase 3: A(mi=3) ----
    a0 = *(const bf16x8*)&LA[LOFF2(wm*128 + 3*32 + l31, 0 + l5)];
    a1 = *(const bf16x8*)&LA[LOFF2(wm*128 + 3*32 + l31, 2 + l5)];
    __builtin_amdgcn_s_barrier();
    __builtin_amdgcn_s_setprio(1);
    MM2(3, a0, a1);
    __builtin_amdgcn_s_setprio(0);

    // ---- tile boundary: counted wait (never 0 in steady state) ----
    if (t < nt - 2){
      asm volatile("s_waitcnt vmcnt(4)" ::: "memory");
      __builtin_amdgcn_s_barrier();
    } else if (t == nt - 2){
      asm volatile("s_waitcnt vmcnt(0)" ::: "memory");
      __builtin_amdgcn_s_barrier();
    }
    buf = buf + 1; if (buf >= 3) buf -= 3;
  }
#undef STG
#undef LOFF2
#undef MM2

  // ---- epilogue (32x32 C/D layout) ----
#pragma unroll
  for (int mi = 0; mi < 4; ++mi){
#pragma unroll
    for (int ni = 0; ni < 2; ++ni){
      const f32x16 a = acc[mi][ni];
      const int c = n0 + wn*64 + ni*32 + l31;
      const float bb = (EPI == 2) ? bias[c] : 0.f;
#pragma unroll
      for (int reg = 0; reg < 16; ++reg){
        const int r = m0 + wm*128 + mi*32 + (reg & 3) + 8*(reg >> 2) + 4*l5;
        if constexpr (EPI == 0){
          ((u16*)Cout)[(size_t)r*N + c] = f2b(a[reg]);
        } else if constexpr (EPI == 2){
          const float xv = a[reg] + bb;
          ((u16*)Cout)[(size_t)r*N + c] = f2b(0.5f * xv * (1.f + erff(xv * 0.70710678118654752f)));
        } else {
          ((float*)Cout)[(size_t)r*N + c] = a[reg];
        }
      }
    }
  }
}

// ---------------- causal flash attention: swapped-QK, KVBLK=64, QBLK=32/wave
// (unchanged from round 9 — exact per-frag mask gates)
__global__ __launch_bounds__(256) void attn_k(const u16* __restrict__ qkv,
                                              u16* __restrict__ ctx){
  __shared__ __attribute__((aligned(16))) u16 Ks[2][64*64];
  __shared__ __attribute__((aligned(16))) u16 Vt[2][64][72];
  __shared__ __attribute__((aligned(16))) u16 Ps[8][16][72];
  const int tid = threadIdx.x, lane = tid & 63, w = tid >> 6;
  const int l15 = lane & 15, l4 = lane >> 4;
  const int b = blockIdx.y >> 4, h = blockIdx.y & 15;
  const int bx = gridDim.x - 1 - blockIdx.x;
  const int q0 = bx * 128;
  const int qw = q0 + w * 32;
  const u16* qb = qkv + (size_t)b * 2048 * 3072 + h * 64;
  const u16* kb = qb + 1024;
  const u16* vb = qb + 2048;

  const bf16x8 qa0 = *(const bf16x8*)&qb[(size_t)(qw + l15) * 3072 + l4 * 8];
  const bf16x8 qa1 = *(const bf16x8*)&qb[(size_t)(qw + l15) * 3072 + 32 + l4 * 8];
  const bf16x8 qb0 = *(const bf16x8*)&qb[(size_t)(qw + 16 + l15) * 3072 + l4 * 8];
  const bf16x8 qb1 = *(const bf16x8*)&qb[(size_t)(qw + 16 + l15) * 3072 + 32 + l4 * 8];

  f32x4 oa[4] = {}, ob[4] = {};
  float mra = -__builtin_inff(), lra = 0.f;
  float mrb = -__builtin_inff(), lrb = 0.f;
  const float CEXP = 0.18033688f;              // 0.125 * log2(e)

  const int T = 2*bx + 2;
  const int vd = tid & 63, vkc = w;

  {
    u16* kd = &Ks[0][0];
#pragma unroll
    for (int s = 0; s < 2; ++s){
      const int r = s*32 + w*8 + (lane >> 3);
      __builtin_amdgcn_global_load_lds(AS1(kb + (size_t)r * 3072 + ((lane & 7) ^ (r & 7)) * 8),
                                       AS3(kd + (s*32 + w*8) * 64), 16, 0, 0);
    }
    u16 vr[16];
#pragma unroll
    for (int i = 0; i < 16; ++i) vr[i] = vb[(size_t)(vkc*16 + i) * 3072 + vd];
    u16x8 va, vb2;
#pragma unroll
    for (int i = 0; i < 8; ++i){ va[i] = vr[i]; vb2[i] = vr[8+i]; }
    *(u16x8*)&Vt[0][vd][vkc*16]     = va;
    *(u16x8*)&Vt[0][vd][vkc*16 + 8] = vb2;
  }
  __syncthreads();

  for (int t = 0; t < T; ++t){
    const int cur = t & 1;
    const int kt = t * 64;

    u16 vr[16];
    if (t + 1 < T){
      const int ktn = kt + 64;
      u16* kd = &Ks[cur ^ 1][0];
#pragma unroll
      for (int s = 0; s < 2; ++s){
        const int r = s*32 + w*8 + (lane >> 3);
        __builtin_amdgcn_global_load_lds(AS1(kb + (size_t)(ktn + r) * 3072 + ((lane & 7) ^ (r & 7)) * 8),
                                         AS3(kd + (s*32 + w*8) * 64), 16, 0, 0);
      }
#pragma unroll
      for (int i = 0; i < 16; ++i) vr[i] = vb[(size_t)(ktn + vkc*16 + i) * 3072 + vd];
    }

    if (kt <= qw + 31){
      f32x4 sta[4] = {}, stb[4] = {};
      __builtin_amdgcn_s_setprio(1);
#pragma unroll
      for (int t4 = 0; t4 < 4; ++t4){
        const int r = t4*16 + l15;
        const int sx = l15 & 7;
        const bf16x8 kf0 = *(const bf16x8*)&Ks[cur][r*64 + ((l4       ^ sx) * 8)];
        const bf16x8 kf1 = *(const bf16x8*)&Ks[cur][r*64 + (((4 + l4) ^ sx) * 8)];
        sta[t4] = __builtin_amdgcn_mfma_f32_16x16x32_bf16(kf0, qa0, sta[t4], 0, 0, 0);
        sta[t4] = __builtin_amdgcn_mfma_f32_16x16x32_bf16(kf1, qa1, sta[t4], 0, 0, 0);
        stb[t4] = __builtin_amdgcn_mfma_f32_16x16x32_bf16(kf0, qb0, stb[t4], 0, 0, 0);
        stb[t4] = __builtin_amdgcn_mfma_f32_16x16x32_bf16(kf1, qb1, stb[t4], 0, 0, 0);
      }
      __builtin_amdgcn_s_setprio(0);

      bf16x8 pa0, pa1, pb0, pb1;
      {
        float sv[16];
#pragma unroll
        for (int t4 = 0; t4 < 4; ++t4)
#pragma unroll
          for (int j = 0; j < 4; ++j) sv[t4*4 + j] = sta[t4][j];
        if (kt + 63 > qw){
          const int qrow = qw + l15;
#pragma unroll
          for (int t4 = 0; t4 < 4; ++t4)
#pragma unroll
            for (int j = 0; j < 4; ++j){
              const int k = kt + t4*16 + l4*4 + j;
              if (k > qrow) sv[t4*4 + j] = -__builtin_inff();
            }
        }
        float x0 = fmaxf(fmaxf(sv[0],  sv[1]),  sv[2]);
        float x1 = fmaxf(fmaxf(sv[3],  sv[4]),  sv[5]);
        float x2 = fmaxf(fmaxf(sv[6],  sv[7]),  sv[8]);
        float x3 = fmaxf(fmaxf(sv[9],  sv[10]), sv[11]);
        float x4 = fmaxf(fmaxf(sv[12], sv[13]), sv[14]);
        float mt = fmaxf(fmaxf(fmaxf(x0, x1), x2), fmaxf(fmaxf(x3, x4), sv[15]));
        mt = fmaxf(mt, __shfl_xor(mt, 16));
        mt = fmaxf(mt, __shfl_xor(mt, 32));
        if (__any(mt > mra + 64.f)){
          const float mn = fmaxf(mra, mt);
          const float sc = fexp2((mra - mn) * CEXP);
          lra *= sc;
          mra = mn;
#pragma unroll
          for (int j = 0; j < 4; ++j){
            const float scj = __shfl(sc, l4*4 + j);
            oa[0][j] *= scj; oa[1][j] *= scj; oa[2][j] *= scj; oa[3][j] *= scj;
          }
        }
        const float mb = -mra * CEXP;
#pragma unroll
        for (int i = 0; i < 16; ++i) sv[i] = fexp2(__builtin_fmaf(sv[i], CEXP, mb));
        {
          float s0 = sv[0]+sv[1], s1 = sv[2]+sv[3], s2 = sv[4]+sv[5], s3 = sv[6]+sv[7];
          float s4 = sv[8]+sv[9], s5 = sv[10]+sv[11], s6 = sv[12]+sv[13], s7 = sv[14]+sv[15];
          float rs = (s0+s1) + (s2+s3) + ((s4+s5) + (s6+s7));
          rs += __shfl_xor(rs, 16);
          rs += __shfl_xor(rs, 32);
          lra += rs;
        }
#pragma unroll
        for (int t4 = 0; t4 < 4; ++t4){
          uint32_t pk0, pk1;
          asm("v_cvt_pk_bf16_f32 %0, %1, %2" : "=v"(pk0) : "v"(sv[t4*4+0]), "v"(sv[t4*4+1]));
          asm("v_cvt_pk_bf16_f32 %0, %1, %2" : "=v"(pk1) : "v"(sv[t4*4+2]), "v"(sv[t4*4+3]));
          *(uint32_t*)&Ps[2*w][l15][t4*16 + l4*4]     = pk0;
          *(uint32_t*)&Ps[2*w][l15][t4*16 + l4*4 + 2] = pk1;
        }
        pa0 = *(const bf16x8*)&Ps[2*w][l15][l4*8];
        pa1 = *(const bf16x8*)&Ps[2*w][l15][32 + l4*8];
      }
      {
        float sv[16];
#pragma unroll
        for (int t4 = 0; t4 < 4; ++t4)
#pragma unroll
          for (int j = 0; j < 4; ++j) sv[t4*4 + j] = stb[t4][j];
        if (kt + 63 > qw + 16){
          const int qrow = qw + 16 + l15;
#pragma unroll
          for (int t4 = 0; t4 < 4; ++t4)
#pragma unroll
            for (int j = 0; j < 4; ++j){
              const int k = kt + t4*16 + l4*4 + j;
              if (k > qrow) sv[t4*4 + j] = -__builtin_inff();
            }
        }
        float x0 = fmaxf(fmaxf(sv[0],  sv[1]),  sv[2]);
        float x1 = fmaxf(fmaxf(sv[3],  sv[4]),  sv[5]);
        float x2 = fmaxf(fmaxf(sv[6],  sv[7]),  sv[8]);
        float x3 = fmaxf(fmaxf(sv[9],  sv[10]), sv[11]);
        float x4 = fmaxf(fmaxf(sv[12], sv[13]), sv[14]);
        float mt = fmaxf(fmaxf(fmaxf(x0, x1), x2), fmaxf(fmaxf(x3, x4), sv[15]));
        mt = fmaxf(mt, __shfl_xor(mt, 16));
        mt = fmaxf(mt, __shfl_xor(mt, 32));
        if (__any(mt > mrb + 64.f)){
          const float mn = fmaxf(mrb, mt);
          const float sc = fexp2((mrb - mn) * CEXP);
          lrb *= sc;
          mrb = mn;
#pragma unroll
          for (int j = 0; j < 4; ++j){
            const float scj = __shfl(sc, l4*4 + j);
            ob[0][j] *= scj; ob[1][j] *= scj; ob[2][j] *= scj; ob[3][j] *= scj;
          }
        }
        const float mb = -mrb * CEXP;
#pragma unroll
        for (int i = 0; i < 16; ++i) sv[i] = fexp2(__builtin_fmaf(sv[i], CEXP, mb));
        {
          float s0 = sv[0]+sv[1], s1 = sv[2]+sv[3], s2 = sv[4]+sv[5], s3 = sv[6]+sv[7];
          float s4 = sv[8]+sv[9], s5 = sv[10]+sv[11], s6 = sv[12]+sv[13], s7 = sv[14]+sv[15];
          float rs = (s0+s1) + (s2+s3) + ((s4+s5) + (s6+s7));
          rs += __shfl_xor(rs, 16);
          rs += __shfl_xor(rs, 32);
          lrb += rs;
        }
#pragma unroll
        for (int t4 = 0; t4 < 4; ++t4){
          uint32_t pk0, pk1;
          asm("v_cvt_pk_bf16_f32 %0, %1, %2" : "=v"(pk0) : "v"(sv[t4*4+0]), "v"(sv[t4*4+1]));
          asm("v_cvt_pk_bf16_f32 %0, %1, %2" : "=v"(pk1) : "v"(sv[t4*4+2]), "v"(sv[t4*4+3]));
          *(uint32_t*)&Ps[2*w+1][l15][t4*16 + l4*4]     = pk0;
          *(uint32_t*)&Ps[2*w+1][l15][t4*16 + l4*4 + 2] = pk1;
        }
        pb0 = *(const bf16x8*)&Ps[2*w+1][l15][l4*8];
        pb1 = *(const bf16x8*)&Ps[2*w+1][l15][32 + l4*8];
      }

      __builtin_amdgcn_s_setprio(1);
#pragma unroll
      for (int dt = 0; dt < 4; ++dt){
        const bf16x8 vf0 = *(const bf16x8*)&Vt[cur][dt*16 + l15][l4*8];
        const bf16x8 vf1 = *(const bf16x8*)&Vt[cur][dt*16 + l15][32 + l4*8];
        oa[dt] = __builtin_amdgcn_mfma_f32_16x16x32_bf16(pa0, vf0, oa[dt], 0, 0, 0);
        oa[dt] = __builtin_amdgcn_mfma_f32_16x16x32_bf16(pa1, vf1, oa[dt], 0, 0, 0);
        ob[dt] = __builtin_amdgcn_mfma_f32_16x16x32_bf16(pb0, vf0, ob[dt], 0, 0, 0);
        ob[dt] = __builtin_amdgcn_mfma_f32_16x16x32_bf16(pb1, vf1, ob[dt], 0, 0, 0);
      }
      __builtin_amdgcn_s_setprio(0);
    }

    if (t + 1 < T){
      u16x8 va, vb2;
#pragma unroll
      for (int i = 0; i < 8; ++i){ va[i] = vr[i]; vb2[i] = vr[8+i]; }
      *(u16x8*)&Vt[cur ^ 1][vd][vkc*16]     = va;
      *(u16x8*)&Vt[cur ^ 1][vd][vkc*16 + 8] = vb2;
    }
    __syncthreads();
  }

  const float inva = 1.f / lra, invb = 1.f / lrb;
#pragma unroll
  for (int j = 0; j < 4; ++j){
    const float ia = __shfl(inva, l4*4 + j);
    const float ib = __shfl(invb, l4*4 + j);
    u16* ca = ctx + (size_t)b * 2048 * 1024 + (size_t)(qw + l4*4 + j) * 1024 + h * 64;
    u16* cb2 = ca + (size_t)16 * 1024;
#pragma unroll
    for (int dt = 0; dt < 4; ++dt){
      ca[dt*16 + l15]  = f2b(oa[dt][j] * ia);
      cb2[dt*16 + l15] = f2b(ob[dt][j] * ib);
    }
  }
}

// ---------------- host
extern "C" void kernel_launch(void* const* d_in, const int* in_sizes, int n_in,
                              void* d_out, int out_size, void* d_ws, size_t ws_size,
                              hipStream_t stream){
  const int*   tokens = (const int*)d_in[0];
  const float* tok_emb= (const float*)d_in[1];
  const float* pos_emb= (const float*)d_in[2];
  const float* Wq  = (const float*)d_in[3];
  const float* Wk  = (const float*)d_in[4];
  const float* Wv  = (const float*)d_in[5];
  const float* Wo  = (const float*)d_in[6];
  const float* ln1g= (const float*)d_in[7];
  const float* ln1b= (const float*)d_in[8];
  const float* ln2g= (const float*)d_in[9];
  const float* ln2b= (const float*)d_in[10];
  const float* W1  = (const float*)d_in[11];
  const float* b1  = (const float*)d_in[12];
  const float* W2  = (const float*)d_in[13];
  const float* b2  = (const float*)d_in[14];
  const float* lnfg= (const float*)d_in[15];
  const float* lnfb= (const float*)d_in[16];
  const float* Wout= (const float*)d_in[17];

  char* ws = (char*)d_ws;
  float* x    = (float*)(ws + 0);            // 4096x1024 f32
  u16*   h    = (u16*)(ws + 16777216);       // 4096x1024 bf16
  u16*   qkv  = (u16*)(ws + 25165824);       // 4096x3072 bf16
  u16*   ctxb = (u16*)(ws + 50331648);       // 4096x1024 bf16
  u16*   h1   = (u16*)(ws + 58720256);       // 4096x4096 bf16
  u16*   wT   = (u16*)(ws + 92274688);       // weights region
  u16*   wqkvT= wT;                          // [3072][1024]
  u16*   woT  = wT + (size_t)3072 * 1024;    // [1024][1024]
  u16*   w1T  = woT + (size_t)1024 * 1024;   // [4096][1024]
  u16*   w2T  = w1T + (size_t)4096 * 1024;   // [1024][4096]
  u16*   woutT= wT;                          // [32000][1024] (reuses region)

  embed_k<<<4096, 256, 0, stream>>>(tokens, tok_emb, pos_emb, x);

  for (int l = 0; l < 6; ++l){
    conv6_k<<<3072, 256, 0, stream>>>(Wq + (size_t)l*1048576, Wk + (size_t)l*1048576,
                                      Wv + (size_t)l*1048576, Wo + (size_t)l*1048576,
                                      W1 + (size_t)l*4194304, W2 + (size_t)l*4194304,
                                      wqkvT, woT, w1T, w2T);

    ln_k<<<4096, 256, 0, stream>>>(x, ln1g + l*1024, ln1b + l*1024, h);
    gemm_bt2<0><<<dim3(16,12), 512, 0, stream>>>(h, wqkvT, qkv, nullptr, 4096, 3072, 1024);
    attn_k<<<dim3(16,32), 256, 0, stream>>>(qkv, ctxb);
    gemm_bt<1><<<dim3(32,8), 256, 0, stream>>>(ctxb, woT, x, nullptr, 4096, 1024, 1024);
    ln_k<<<4096, 256, 0, stream>>>(x, ln2g + l*1024, ln2b + l*1024, h);
    gemm_bt2<2><<<dim3(16,16), 512, 0, stream>>>(h, w1T, h1, b1 + l*4096, 4096, 4096, 1024);
    gemm_bt<1><<<dim3(32,8), 256, 0, stream>>>(h1, w2T, x, b2 + l*1024, 4096, 1024, 4096);
  }

  ln_k<<<4096, 256, 0, stream>>>(x, lnfg, lnfb, h);
  conv_t<<<dim3(500,16), 256, 0, stream>>>(Wout, woutT, 1024, 32000);
  gemm_bt2<3><<<dim3(16,125), 512, 0, stream>>>(h, woutT, (float*)d_out, nullptr, 4096, 32000, 1024);
}

// Round 12
// 2057.179 us; speedup vs baseline: 1.2633x; 1.2633x over previous
//
#include <hip/hip_runtime.h>
#include <stdint.h>

typedef unsigned short u16;
typedef __bf16 bf16x8 __attribute__((ext_vector_type(8)));
typedef u16   u16x8  __attribute__((ext_vector_type(8)));
typedef float f32x4  __attribute__((ext_vector_type(4)));

#define AS1(p) (const __attribute__((address_space(1))) void*)(p)
#define AS3(p) (__attribute__((address_space(3))) void*)(p)

__device__ __forceinline__ u16 f2b(float f){
  uint32_t u = __builtin_bit_cast(uint32_t, f);
  u = (u + 0x7FFFu + ((u >> 16) & 1u)) >> 16;
  return (u16)u;
}
__device__ __forceinline__ float fexp2(float x){
#if __has_builtin(__builtin_amdgcn_exp2f)
  return __builtin_amdgcn_exp2f(x);
#else
  return exp2f(x);
#endif
}

// ---------------- embedding
__global__ __launch_bounds__(256) void embed_k(const int* __restrict__ tokens,
                                               const float* __restrict__ te,
                                               const float* __restrict__ pe,
                                               float* __restrict__ x){
  const int n = blockIdx.x, tid = threadIdx.x;
  const int tok = tokens[n];
  float4 a = *(const float4*)&te[(size_t)tok * 1024 + tid * 4];
  const float4 p = *(const float4*)&pe[(size_t)(n & 2047) * 1024 + tid * 4];
  a.x += p.x; a.y += p.y; a.z += p.z; a.w += p.w;
  *(float4*)&x[(size_t)n * 1024 + tid * 4] = a;
}

// ---------------- LayerNorm (D=1024), f32 in -> bf16 out
__global__ __launch_bounds__(256) void ln_k(const float* __restrict__ x,
                                            const float* __restrict__ g,
                                            const float* __restrict__ b,
                                            u16* __restrict__ h){
  const int row = blockIdx.x, tid = threadIdx.x;
  const float4 v = *(const float4*)&x[(size_t)row * 1024 + tid * 4];
  float s = v.x + v.y + v.z + v.w;
  float q = v.x*v.x + v.y*v.y + v.z*v.z + v.w*v.w;
#pragma unroll
  for (int m = 32; m; m >>= 1){ s += __shfl_xor(s, m); q += __shfl_xor(q, m); }
  __shared__ float ss[4], qq[4];
  if ((tid & 63) == 0){ ss[tid >> 6] = s; qq[tid >> 6] = q; }
  __syncthreads();
  s = ss[0] + ss[1] + ss[2] + ss[3];
  q = qq[0] + qq[1] + qq[2] + qq[3];
  const float mean = s * (1.f/1024.f);
  const float var  = q * (1.f/1024.f) - mean*mean;
  const float rstd = rsqrtf(var + 1e-5f);
  const float4 gv = *(const float4*)&g[tid*4];
  const float4 bv = *(const float4*)&b[tid*4];
  ushort4 o;
  o.x = f2b((v.x-mean)*rstd*gv.x + bv.x);
  o.y = f2b((v.y-mean)*rstd*gv.y + bv.y);
  o.z = f2b((v.z-mean)*rstd*gv.z + bv.z);
  o.w = f2b((v.w-mean)*rstd*gv.w + bv.w);
  *(ushort4*)&h[(size_t)row * 1024 + tid * 4] = o;
}

// ---------------- shared transpose-convert tile body
__device__ __forceinline__ void conv_tile(const float* __restrict__ src,
                                          u16* __restrict__ dst,
                                          int R, int C, int bx, int by,
                                          u16 (*t)[72], int tid){
  const int r0 = by * 64, c0 = bx * 64;
  const int row = tid >> 4, col4 = tid & 15;
#pragma unroll
  for (int p = 0; p < 4; ++p){
    const int r = row + p * 16;
    const float4 v = *(const float4*)&src[(size_t)(r0 + r) * C + c0 + col4 * 4];
    t[r][col4*4+0] = f2b(v.x); t[r][col4*4+1] = f2b(v.y);
    t[r][col4*4+2] = f2b(v.z); t[r][col4*4+3] = f2b(v.w);
  }
  __syncthreads();
#pragma unroll
  for (int p = 0; p < 4; ++p){
    const int rr = row + p * 16;
    ushort4 w;
    w.x = t[col4*4+0][rr]; w.y = t[col4*4+1][rr];
    w.z = t[col4*4+2][rr]; w.w = t[col4*4+3][rr];
    *(ushort4*)&dst[(size_t)(c0 + rr) * R + r0 + col4 * 4] = w;
  }
}

__global__ __launch_bounds__(256) void conv_t(const float* __restrict__ src,
                                              u16* __restrict__ dst,
                                              int R, int C){
  __shared__ u16 t[64][72];
  conv_tile(src, dst, R, C, blockIdx.x, blockIdx.y, t, threadIdx.x);
}

__global__ __launch_bounds__(256) void conv6_k(const float* __restrict__ Wq,
                                               const float* __restrict__ Wk,
                                               const float* __restrict__ Wv,
                                               const float* __restrict__ Wo,
                                               const float* __restrict__ W1,
                                               const float* __restrict__ W2,
                                               u16* __restrict__ qkvT,
                                               u16* __restrict__ woT,
                                               u16* __restrict__ w1T,
                                               u16* __restrict__ w2T){
  __shared__ u16 t[64][72];
  const int id = blockIdx.x;
  const float* src; u16* dst; int R, C, bx, by;
  if (id < 1024){
    R = 1024; C = 1024;
    const int m = id >> 8, tt = id & 255; bx = tt & 15; by = tt >> 4;
    if (m == 0){ src = Wq; dst = qkvT; }
    else if (m == 1){ src = Wk; dst = qkvT + 1048576; }
    else if (m == 2){ src = Wv; dst = qkvT + 2097152; }
    else { src = Wo; dst = woT; }
  } else if (id < 2048){
    const int tt = id - 1024; R = 1024; C = 4096; bx = tt & 63; by = tt >> 6;
    src = W1; dst = w1T;
  } else {
    const int tt = id - 2048; R = 4096; C = 1024; bx = tt & 15; by = tt >> 4;
    src = W2; dst = w2T;
  }
  conv_tile(src, dst, R, C, bx, by, t, threadIdx.x);
}

// ---------------- 128x128 bf16 MFMA GEMM — 3-slot ring, counted vmcnt, 2 phases
// Same verified machinery as gemm_bt2 (rounds 7/9: 0 conflicts, race-free):
// BK=32, slot(t)=t%3, stage tile t+2 during tile t, boundary vmcnt(4).
// 4 waves (2M x 2N), per-wave C = 64x64 (4x4 frags of 16x16x32).
// LOFF/stager mapping byte-identical logic to the round-9 verified kernel.
// EPI: 0 = store bf16, 1 = f32 += acc (+bias), 2 = gelu(acc+bias) bf16, 3 = store f32
template<int EPI>
__global__ __launch_bounds__(256) void gemm_bt(const u16* __restrict__ A,
                                               const u16* __restrict__ BT,
                                               void* __restrict__ Cout,
                                               const float* __restrict__ bias,
                                               int M, int N, int K){
  __shared__ __attribute__((aligned(16))) u16 Ls[3][2][128*32];  // 48 KiB
  const int tid = threadIdx.x;
  const int lane = tid & 63, wave = tid >> 6;
  const int m0 = blockIdx.x * 128, n0 = blockIdx.y * 128;
  const int wm = wave >> 1, wn = wave & 1;
  const int l15 = lane & 15, l4 = lane >> 4;

  // write-side inverse swizzle (verified round 7/9): lane -> (row, chunk)
  const int su  = (lane >> 3) & 7;
  const int c8  = (lane & 7) ^ su;
  const int rloc= ((lane >> 3) << 1) | (c8 >> 2);
  const int xl  = (c8 & 3) * 8;

  const u16* Asrc = A  + (size_t)(m0 + wave*16 + rloc) * K + xl;
  const u16* Bsrc = BT + (size_t)(n0 + wave*16 + rloc) * K + xl;
  char* lds0 = (char*)&Ls[0][0][0];
  const int wb = wave * 1024;

  // read-side: physical elem offset of logical (row r, chunk x=l4)
#define LOFF(r) (((r) >> 1)*64 + (((((((r) & 1) << 2) | l4)) ^ (((r) >> 1) & 7))*8))

#define STG(sb, k0, L) do{ \
    __builtin_amdgcn_global_load_lds(AS1(Asrc + (size_t)((L)*64)*K + (size_t)(k0)), \
        AS3(lds0 + (sb)*16384 +        (L)*4096 + wb), 16, 0, 0); \
    __builtin_amdgcn_global_load_lds(AS1(Bsrc + (size_t)((L)*64)*K + (size_t)(k0)), \
        AS3(lds0 + (sb)*16384 + 8192 + (L)*4096 + wb), 16, 0, 0); \
  }while(0)

  f32x4 acc[4][4] = {};
  const int nt = K >> 5;

  // prologue: tiles 0,1 -> slots 0,1 (8 loads); wait tile 0 (tile 1 in flight)
  STG(0, 0, 0);  STG(0, 0, 1);
  STG(1, 32, 0); STG(1, 32, 1);
  asm volatile("s_waitcnt vmcnt(4)" ::: "memory");
  __builtin_amdgcn_s_barrier();

  int buf = 0;
  for (int t = 0; t < nt; ++t){
    const u16* LA = &Ls[buf][0][0];
    const u16* LB = &Ls[buf][1][0];
    int sb = buf + 2; if (sb >= 3) sb -= 3;
    const int kn = (t + 2) << 5;
    const bool st = (t + 2) < nt;

    bf16x8 bfv[4], a0, a1;
    // ---- phase 0: B frags + A0-1 ; stage half 0 of tile t+2 ----
#pragma unroll
    for (int ni = 0; ni < 4; ++ni)
      bfv[ni] = *(const bf16x8*)&LB[LOFF(wn*64 + ni*16 + l15)];
    a0 = *(const bf16x8*)&LA[LOFF(wm*64 + 0*16 + l15)];
    a1 = *(const bf16x8*)&LA[LOFF(wm*64 + 1*16 + l15)];
    if (st) STG(sb, kn, 0);
    __builtin_amdgcn_s_barrier();
    __builtin_amdgcn_s_setprio(1);
#pragma unroll
    for (int ni = 0; ni < 4; ++ni){
      acc[0][ni] = __builtin_amdgcn_mfma_f32_16x16x32_bf16(a0, bfv[ni], acc[0][ni], 0, 0, 0);
      acc[1][ni] = __builtin_amdgcn_mfma_f32_16x16x32_bf16(a1, bfv[ni], acc[1][ni], 0, 0, 0);
    }
    __builtin_amdgcn_s_setprio(0);

    // ---- phase 1: A2-3 ; stage half 1 ----
    a0 = *(const bf16x8*)&LA[LOFF(wm*64 + 2*16 + l15)];
    a1 = *(const bf16x8*)&LA[LOFF(wm*64 + 3*16 + l15)];
    if (st) STG(sb, kn, 1);
    __builtin_amdgcn_s_barrier();
    __builtin_amdgcn_s_setprio(1);
#pragma unroll
    for (int ni = 0; ni < 4; ++ni){
      acc[2][ni] = __builtin_amdgcn_mfma_f32_16x16x32_bf16(a0, bfv[ni], acc[2][ni], 0, 0, 0);
      acc[3][ni] = __builtin_amdgcn_mfma_f32_16x16x32_bf16(a1, bfv[ni], acc[3][ni], 0, 0, 0);
    }
    __builtin_amdgcn_s_setprio(0);

    // ---- tile boundary: counted wait (never 0 in steady state) ----
    if (t < nt - 2){
      asm volatile("s_waitcnt vmcnt(4)" ::: "memory");
      __builtin_amdgcn_s_barrier();
    } else if (t == nt - 2){
      asm volatile("s_waitcnt vmcnt(0)" ::: "memory");
      __builtin_amdgcn_s_barrier();
    }
    buf = buf + 1; if (buf >= 3) buf -= 3;
  }
#undef STG
#undef LOFF

#pragma unroll
  for (int mi = 0; mi < 4; ++mi){
    const int r = m0 + wm*64 + mi*16 + l4*4;
#pragma unroll
    for (int ni = 0; ni < 4; ++ni){
      const int c = n0 + wn*64 + ni*16 + l15;
      const f32x4 a = acc[mi][ni];
      if constexpr (EPI == 0){
        u16* C = (u16*)Cout;
#pragma unroll
        for (int j = 0; j < 4; ++j) C[(size_t)(r+j)*N + c] = f2b(a[j]);
      } else if constexpr (EPI == 1){
        float* C = (float*)Cout;
        const float bb = bias ? bias[c] : 0.f;
#pragma unroll
        for (int j = 0; j < 4; ++j){ const size_t o = (size_t)(r+j)*N + c; C[o] += a[j] + bb; }
      } else if constexpr (EPI == 2){
        u16* C = (u16*)Cout;
        const float bb = bias[c];
#pragma unroll
        for (int j = 0; j < 4; ++j){
          const float xv = a[j] + bb;
          C[(size_t)(r+j)*N + c] = f2b(0.5f * xv * (1.f + erff(xv * 0.70710678118654752f)));
        }
      } else {
        float* C = (float*)Cout;
#pragma unroll
        for (int j = 0; j < 4; ++j) C[(size_t)(r+j)*N + c] = a[j];
      }
    }
  }
}

// ---------------- 256x256 tile, BK=32, 3-slot ring, counted-vmcnt, 4 fine phases/tile
// (round-9 verified version, verbatim: 16x16x32 MFMA, 0 bank conflicts)
template<int EPI>
__global__ __launch_bounds__(512) void gemm_bt2(const u16* __restrict__ A,
                                                const u16* __restrict__ BT,
                                                void* __restrict__ Cout,
                                                const float* __restrict__ bias,
                                                int M, int N, int K){
  __shared__ __attribute__((aligned(16))) u16 Ls[3][2][256*32];  // 96 KiB
  const int tid = threadIdx.x;
  const int lane = tid & 63, wave = tid >> 6;
  const int m0 = blockIdx.x * 256, n0 = blockIdx.y * 256;
  const int wm = wave >> 2, wn = wave & 3;
  const int l15 = lane & 15, l4 = lane >> 4;

  // write-side inverse swizzle: this lane's global (row, chunk)
  const int su  = (lane >> 3) & 7;
  const int c8  = (lane & 7) ^ su;
  const int rloc= ((lane >> 3) << 1) | (c8 >> 2);
  const int xl  = (c8 & 3) * 8;

  const u16* Asrc = A  + (size_t)(m0 + wave*16 + rloc) * K + xl;
  const u16* Bsrc = BT + (size_t)(n0 + wave*16 + rloc) * K + xl;
  char* lds0 = (char*)&Ls[0][0][0];
  const int wb = wave * 1024;

#define LOFF(r) (((r) >> 1)*64 + (((((((r) & 1) << 2) | l4)) ^ (((r) >> 1) & 7))*8))

#define STG(sb, k0, L) do{ \
    __builtin_amdgcn_global_load_lds(AS1(Asrc + (size_t)((L)*128)*K + (size_t)(k0)), \
        AS3(lds0 + (sb)*32768 +         (L)*8192 + wb), 16, 0, 0); \
    __builtin_amdgcn_global_load_lds(AS1(Bsrc + (size_t)((L)*128)*K + (size_t)(k0)), \
        AS3(lds0 + (sb)*32768 + 16384 + (L)*8192 + wb), 16, 0, 0); \
  }while(0)

#define MM(mi, a) do{ \
    acc[mi][0] = __builtin_amdgcn_mfma_f32_16x16x32_bf16((a), bf[0], acc[mi][0], 0, 0, 0); \
    acc[mi][1] = __builtin_amdgcn_mfma_f32_16x16x32_bf16((a), bf[1], acc[mi][1], 0, 0, 0); \
    acc[mi][2] = __builtin_amdgcn_mfma_f32_16x16x32_bf16((a), bf[2], acc[mi][2], 0, 0, 0); \
    acc[mi][3] = __builtin_amdgcn_mfma_f32_16x16x32_bf16((a), bf[3], acc[mi][3], 0, 0, 0); \
  }while(0)

  f32x4 acc[8][4] = {};
  const int nt = K >> 5;

  // prologue: tiles 0,1 -> slots 0,1; wait tile 0 (tile 1 stays in flight)
  STG(0, 0, 0);  STG(0, 0, 1);
  STG(1, 32, 0); STG(1, 32, 1);
  asm volatile("s_waitcnt vmcnt(4)" ::: "memory");
  __builtin_amdgcn_s_barrier();

  int buf = 0;
  for (int t = 0; t < nt; ++t){
    const u16* LA = &Ls[buf][0][0];
    const u16* LB = &Ls[buf][1][0];
    int sb = buf + 2; if (sb >= 3) sb -= 3;
    const int kn = (t + 2) << 5;
    const bool st = (t + 2) < nt;

    bf16x8 bf[4], af0, af1;
    // ---- phase 0: B frags + A0-1 ; stage half 0 of tile t+2 ----
#pragma unroll
    for (int ni = 0; ni < 4; ++ni)
      bf[ni] = *(const bf16x8*)&LB[LOFF(wn*64 + ni*16 + l15)];
    af0 = *(const bf16x8*)&LA[LOFF(wm*128 + 0*16 + l15)];
    af1 = *(const bf16x8*)&LA[LOFF(wm*128 + 1*16 + l15)];
    if (st) STG(sb, kn, 0);
    __builtin_amdgcn_s_barrier();
    __builtin_amdgcn_s_setprio(1);
    MM(0, af0); MM(1, af1);
    __builtin_amdgcn_s_setprio(0);

    // ---- phase 1: A2-3 ----
    af0 = *(const bf16x8*)&LA[LOFF(wm*128 + 2*16 + l15)];
    af1 = *(const bf16x8*)&LA[LOFF(wm*128 + 3*16 + l15)];
    __builtin_amdgcn_s_barrier();
    __builtin_amdgcn_s_setprio(1);
    MM(2, af0); MM(3, af1);
    __builtin_amdgcn_s_setprio(0);

    // ---- phase 2: A4-5 ; stage half 1 ----
    af0 = *(const bf16x8*)&LA[LOFF(wm*128 + 4*16 + l15)];
    af1 = *(const bf16x8*)&LA[LOFF(wm*128 + 5*16 + l15)];
    if (st) STG(sb, kn, 1);
    __builtin_amdgcn_s_barrier();
    __builtin_amdgcn_s_setprio(1);
    MM(4, af0); MM(5, af1);
    __builtin_amdgcn_s_setprio(0);

    // ---- phase 3: A6-7 ----
    af0 = *(const bf16x8*)&LA[LOFF(wm*128 + 6*16 + l15)];
    af1 = *(const bf16x8*)&LA[LOFF(wm*128 + 7*16 + l15)];
    __builtin_amdgcn_s_barrier();
    __builtin_amdgcn_s_setprio(1);
    MM(6, af0); MM(7, af1);
    __builtin_amdgcn_s_setprio(0);

    // ---- tile boundary: counted wait (never 0 in steady state) ----
    if (t < nt - 2){
      asm volatile("s_waitcnt vmcnt(4)" ::: "memory");
      __builtin_amdgcn_s_barrier();
    } else if (t == nt - 2){
      asm volatile("s_waitcnt vmcnt(0)" ::: "memory");
      __builtin_amdgcn_s_barrier();
    }
    buf = buf + 1; if (buf >= 3) buf -= 3;
  }
#undef STG
#undef LOFF
#undef MM

  // ---- epilogue ----
#pragma unroll
  for (int mi = 0; mi < 8; ++mi){
    const int r = m0 + wm*128 + mi*16 + l4*4;
#pragma unroll
    for (int ni = 0; ni < 4; ++ni){
      const int c = n0 + wn*64 + ni*16 + l15;
      const f32x4 a = acc[mi][ni];
      if constexpr (EPI == 0){
        u16* C = (u16*)Cout;
#pragma unroll
        for (int j = 0; j < 4; ++j) C[(size_t)(r+j)*N + c] = f2b(a[j]);
      } else if constexpr (EPI == 2){
        u16* C = (u16*)Cout;
        const float bb = bias[c];
#pragma unroll
        for (int j = 0; j < 4; ++j){
          const float xv = a[j] + bb;
          C[(size_t)(r+j)*N + c] = f2b(0.5f * xv * (1.f + erff(xv * 0.70710678118654752f)));
        }
      } else {
        float* C = (float*)Cout;
#pragma unroll
        for (int j = 0; j < 4; ++j) C[(size_t)(r+j)*N + c] = a[j];
      }
    }
  }
}

// ---------------- causal flash attention: swapped-QK, KVBLK=64, QBLK=32/wave
// (round-9 verified version — exact per-frag mask gates)
__global__ __launch_bounds__(256) void attn_k(const u16* __restrict__ qkv,
                                              u16* __restrict__ ctx){
  __shared__ __attribute__((aligned(16))) u16 Ks[2][64*64];
  __shared__ __attribute__((aligned(16))) u16 Vt[2][64][72];
  __shared__ __attribute__((aligned(16))) u16 Ps[8][16][72];
  const int tid = threadIdx.x, lane = tid & 63, w = tid >> 6;
  const int l15 = lane & 15, l4 = lane >> 4;
  const int b = blockIdx.y >> 4, h = blockIdx.y & 15;
  const int bx = gridDim.x - 1 - blockIdx.x;
  const int q0 = bx * 128;
  const int qw = q0 + w * 32;
  const u16* qb = qkv + (size_t)b * 2048 * 3072 + h * 64;
  const u16* kb = qb + 1024;
  const u16* vb = qb + 2048;

  const bf16x8 qa0 = *(const bf16x8*)&qb[(size_t)(qw + l15) * 3072 + l4 * 8];
  const bf16x8 qa1 = *(const bf16x8*)&qb[(size_t)(qw + l15) * 3072 + 32 + l4 * 8];
  const bf16x8 qb0 = *(const bf16x8*)&qb[(size_t)(qw + 16 + l15) * 3072 + l4 * 8];
  const bf16x8 qb1 = *(const bf16x8*)&qb[(size_t)(qw + 16 + l15) * 3072 + 32 + l4 * 8];

  f32x4 oa[4] = {}, ob[4] = {};
  float mra = -__builtin_inff(), lra = 0.f;
  float mrb = -__builtin_inff(), lrb = 0.f;
  const float CEXP = 0.18033688f;              // 0.125 * log2(e)

  const int T = 2*bx + 2;
  const int vd = tid & 63, vkc = w;

  {
    u16* kd = &Ks[0][0];
#pragma unroll
    for (int s = 0; s < 2; ++s){
      const int r = s*32 + w*8 + (lane >> 3);
      __builtin_amdgcn_global_load_lds(AS1(kb + (size_t)r * 3072 + ((lane & 7) ^ (r & 7)) * 8),
                                       AS3(kd + (s*32 + w*8) * 64), 16, 0, 0);
    }
    u16 vr[16];
#pragma unroll
    for (int i = 0; i < 16; ++i) vr[i] = vb[(size_t)(vkc*16 + i) * 3072 + vd];
    u16x8 va, vb2;
#pragma unroll
    for (int i = 0; i < 8; ++i){ va[i] = vr[i]; vb2[i] = vr[8+i]; }
    *(u16x8*)&Vt[0][vd][vkc*16]     = va;
    *(u16x8*)&Vt[0][vd][vkc*16 + 8] = vb2;
  }
  __syncthreads();

  for (int t = 0; t < T; ++t){
    const int cur = t & 1;
    const int kt = t * 64;

    u16 vr[16];
    if (t + 1 < T){
      const int ktn = kt + 64;
      u16* kd = &Ks[cur ^ 1][0];
#pragma unroll
      for (int s = 0; s < 2; ++s){
        const int r = s*32 + w*8 + (lane >> 3);
        __builtin_amdgcn_global_load_lds(AS1(kb + (size_t)(ktn + r) * 3072 + ((lane & 7) ^ (r & 7)) * 8),
                                         AS3(kd + (s*32 + w*8) * 64), 16, 0, 0);
      }
#pragma unroll
      for (int i = 0; i < 16; ++i) vr[i] = vb[(size_t)(ktn + vkc*16 + i) * 3072 + vd];
    }

    if (kt <= qw + 31){
      f32x4 sta[4] = {}, stb[4] = {};
      __builtin_amdgcn_s_setprio(1);
#pragma unroll
      for (int t4 = 0; t4 < 4; ++t4){
        const int r = t4*16 + l15;
        const int sx = l15 & 7;
        const bf16x8 kf0 = *(const bf16x8*)&Ks[cur][r*64 + ((l4       ^ sx) * 8)];
        const bf16x8 kf1 = *(const bf16x8*)&Ks[cur][r*64 + (((4 + l4) ^ sx) * 8)];
        sta[t4] = __builtin_amdgcn_mfma_f32_16x16x32_bf16(kf0, qa0, sta[t4], 0, 0, 0);
        sta[t4] = __builtin_amdgcn_mfma_f32_16x16x32_bf16(kf1, qa1, sta[t4], 0, 0, 0);
        stb[t4] = __builtin_amdgcn_mfma_f32_16x16x32_bf16(kf0, qb0, stb[t4], 0, 0, 0);
        stb[t4] = __builtin_amdgcn_mfma_f32_16x16x32_bf16(kf1, qb1, stb[t4], 0, 0, 0);
      }
      __builtin_amdgcn_s_setprio(0);

      bf16x8 pa0, pa1, pb0, pb1;
      {
        float sv[16];
#pragma unroll
        for (int t4 = 0; t4 < 4; ++t4)
#pragma unroll
          for (int j = 0; j < 4; ++j) sv[t4*4 + j] = sta[t4][j];
        if (kt + 63 > qw){
          const int qrow = qw + l15;
#pragma unroll
          for (int t4 = 0; t4 < 4; ++t4)
#pragma unroll
            for (int j = 0; j < 4; ++j){
              const int k = kt + t4*16 + l4*4 + j;
              if (k > qrow) sv[t4*4 + j] = -__builtin_inff();
            }
        }
        float x0 = fmaxf(fmaxf(sv[0],  sv[1]),  sv[2]);
        float x1 = fmaxf(fmaxf(sv[3],  sv[4]),  sv[5]);
        float x2 = fmaxf(fmaxf(sv[6],  sv[7]),  sv[8]);
        float x3 = fmaxf(fmaxf(sv[9],  sv[10]), sv[11]);
        float x4 = fmaxf(fmaxf(sv[12], sv[13]), sv[14]);
        float mt = fmaxf(fmaxf(fmaxf(x0, x1), x2), fmaxf(fmaxf(x3, x4), sv[15]));
        mt = fmaxf(mt, __shfl_xor(mt, 16));
        mt = fmaxf(mt, __shfl_xor(mt, 32));
        if (__any(mt > mra + 64.f)){
          const float mn = fmaxf(mra, mt);
          const float sc = fexp2((mra - mn) * CEXP);
          lra *= sc;
          mra = mn;
#pragma unroll
          for (int j = 0; j < 4; ++j){
            const float scj = __shfl(sc, l4*4 + j);
            oa[0][j] *= scj; oa[1][j] *= scj; oa[2][j] *= scj; oa[3][j] *= scj;
          }
        }
        const float mb = -mra * CEXP;
#pragma unroll
        for (int i = 0; i < 16; ++i) sv[i] = fexp2(__builtin_fmaf(sv[i], CEXP, mb));
        {
          float s0 = sv[0]+sv[1], s1 = sv[2]+sv[3], s2 = sv[4]+sv[5], s3 = sv[6]+sv[7];
          float s4 = sv[8]+sv[9], s5 = sv[10]+sv[11], s6 = sv[12]+sv[13], s7 = sv[14]+sv[15];
          float rs = (s0+s1) + (s2+s3) + ((s4+s5) + (s6+s7));
          rs += __shfl_xor(rs, 16);
          rs += __shfl_xor(rs, 32);
          lra += rs;
        }
#pragma unroll
        for (int t4 = 0; t4 < 4; ++t4){
          uint32_t pk0, pk1;
          asm("v_cvt_pk_bf16_f32 %0, %1, %2" : "=v"(pk0) : "v"(sv[t4*4+0]), "v"(sv[t4*4+1]));
          asm("v_cvt_pk_bf16_f32 %0, %1, %2" : "=v"(pk1) : "v"(sv[t4*4+2]), "v"(sv[t4*4+3]));
          *(uint32_t*)&Ps[2*w][l15][t4*16 + l4*4]     = pk0;
          *(uint32_t*)&Ps[2*w][l15][t4*16 + l4*4 + 2] = pk1;
        }
        pa0 = *(const bf16x8*)&Ps[2*w][l15][l4*8];
        pa1 = *(const bf16x8*)&Ps[2*w][l15][32 + l4*8];
      }
      {
        float sv[16];
#pragma unroll
        for (int t4 = 0; t4 < 4; ++t4)
#pragma unroll
          for (int j = 0; j < 4; ++j) sv[t4*4 + j] = stb[t4][j];
        if (kt + 63 > qw + 16){
          const int qrow = qw + 16 + l15;
#pragma unroll
          for (int t4 = 0; t4 < 4; ++t4)
#pragma unroll
            for (int j = 0; j < 4; ++j){
              const int k = kt + t4*16 + l4*4 + j;
              if (k > qrow) sv[t4*4 + j] = -__builtin_inff();
            }
        }
        float x0 = fmaxf(fmaxf(sv[0],  sv[1]),  sv[2]);
        float x1 = fmaxf(fmaxf(sv[3],  sv[4]),  sv[5]);
        float x2 = fmaxf(fmaxf(sv[6],  sv[7]),  sv[8]);
        float x3 = fmaxf(fmaxf(sv[9],  sv[10]), sv[11]);
        float x4 = fmaxf(fmaxf(sv[12], sv[13]), sv[14]);
        float mt = fmaxf(fmaxf(fmaxf(x0, x1), x2), fmaxf(fmaxf(x3, x4), sv[15]));
        mt = fmaxf(mt, __shfl_xor(mt, 16));
        mt = fmaxf(mt, __shfl_xor(mt, 32));
        if (__any(mt > mrb + 64.f)){
          const float mn = fmaxf(mrb, mt);
          const float sc = fexp2((mrb - mn) * CEXP);
          lrb *= sc;
          mrb = mn;
#pragma unroll
          for (int j = 0; j < 4; ++j){
            const float scj = __shfl(sc, l4*4 + j);
            ob[0][j] *= scj; ob[1][j] *= scj; ob[2][j] *= scj; ob[3][j] *= scj;
          }
        }
        const float mb = -mrb * CEXP;
#pragma unroll
        for (int i = 0; i < 16; ++i) sv[i] = fexp2(__builtin_fmaf(sv[i], CEXP, mb));
        {
          float s0 = sv[0]+sv[1], s1 = sv[2]+sv[3], s2 = sv[4]+sv[5], s3 = sv[6]+sv[7];
          float s4 = sv[8]+sv[9], s5 = sv[10]+sv[11], s6 = sv[12]+sv[13], s7 = sv[14]+sv[15];
          float rs = (s0+s1) + (s2+s3) + ((s4+s5) + (s6+s7));
          rs += __shfl_xor(rs, 16);
          rs += __shfl_xor(rs, 32);
          lrb += rs;
        }
#pragma unroll
        for (int t4 = 0; t4 < 4; ++t4){
          uint32_t pk0, pk1;
          asm("v_cvt_pk_bf16_f32 %0, %1, %2" : "=v"(pk0) : "v"(sv[t4*4+0]), "v"(sv[t4*4+1]));
          asm("v_cvt_pk_bf16_f32 %0, %1, %2" : "=v"(pk1) : "v"(sv[t4*4+2]), "v"(sv[t4*4+3]));
          *(uint32_t*)&Ps[2*w+1][l15][t4*16 + l4*4]     = pk0;
          *(uint32_t*)&Ps[2*w+1][l15][t4*16 + l4*4 + 2] = pk1;
        }
        pb0 = *(const bf16x8*)&Ps[2*w+1][l15][l4*8];
        pb1 = *(const bf16x8*)&Ps[2*w+1][l15][32 + l4*8];
      }

      __builtin_amdgcn_s_setprio(1);
#pragma unroll
      for (int dt = 0; dt < 4; ++dt){
        const bf16x8 vf0 = *(const bf16x8*)&Vt[cur][dt*16 + l15][l4*8];
        const bf16x8 vf1 = *(const bf16x8*)&Vt[cur][dt*16 + l15][32 + l4*8];
        oa[dt] = __builtin_amdgcn_mfma_f32_16x16x32_bf16(pa0, vf0, oa[dt], 0, 0, 0);
        oa[dt] = __builtin_amdgcn_mfma_f32_16x16x32_bf16(pa1, vf1, oa[dt], 0, 0, 0);
        ob[dt] = __builtin_amdgcn_mfma_f32_16x16x32_bf16(pb0, vf0, ob[dt], 0, 0, 0);
        ob[dt] = __builtin_amdgcn_mfma_f32_16x16x32_bf16(pb1, vf1, ob[dt], 0, 0, 0);
      }
      __builtin_amdgcn_s_setprio(0);
    }

    if (t + 1 < T){
      u16x8 va, vb2;
#pragma unroll
      for (int i = 0; i < 8; ++i){ va[i] = vr[i]; vb2[i] = vr[8+i]; }
      *(u16x8*)&Vt[cur ^ 1][vd][vkc*16]     = va;
      *(u16x8*)&Vt[cur ^ 1][vd][vkc*16 + 8] = vb2;
    }
    __syncthreads();
  }

  const float inva = 1.f / lra, invb = 1.f / lrb;
#pragma unroll
  for (int j = 0; j < 4; ++j){
    const float ia = __shfl(inva, l4*4 + j);
    const float ib = __shfl(invb, l4*4 + j);
    u16* ca = ctx + (size_t)b * 2048 * 1024 + (size_t)(qw + l4*4 + j) * 1024 + h * 64;
    u16* cb2 = ca + (size_t)16 * 1024;
#pragma unroll
    for (int dt = 0; dt < 4; ++dt){
      ca[dt*16 + l15]  = f2b(oa[dt][j] * ia);
      cb2[dt*16 + l15] = f2b(ob[dt][j] * ib);
    }
  }
}

// ---------------- host
extern "C" void kernel_launch(void* const* d_in, const int* in_sizes, int n_in,
                              void* d_out, int out_size, void* d_ws, size_t ws_size,
                              hipStream_t stream){
  const int*   tokens = (const int*)d_in[0];
  const float* tok_emb= (const float*)d_in[1];
  const float* pos_emb= (const float*)d_in[2];
  const float* Wq  = (const float*)d_in[3];
  const float* Wk  = (const float*)d_in[4];
  const float* Wv  = (const float*)d_in[5];
  const float* Wo  = (const float*)d_in[6];
  const float* ln1g= (const float*)d_in[7];
  const float* ln1b= (const float*)d_in[8];
  const float* ln2g= (const float*)d_in[9];
  const float* ln2b= (const float*)d_in[10];
  const float* W1  = (const float*)d_in[11];
  const float* b1  = (const float*)d_in[12];
  const float* W2  = (const float*)d_in[13];
  const float* b2  = (const float*)d_in[14];
  const float* lnfg= (const float*)d_in[15];
  const float* lnfb= (const float*)d_in[16];
  const float* Wout= (const float*)d_in[17];

  char* ws = (char*)d_ws;
  float* x    = (float*)(ws + 0);            // 4096x1024 f32
  u16*   h    = (u16*)(ws + 16777216);       // 4096x1024 bf16
  u16*   qkv  = (u16*)(ws + 25165824);       // 4096x3072 bf16
  u16*   ctxb = (u16*)(ws + 50331648);       // 4096x1024 bf16
  u16*   h1   = (u16*)(ws + 58720256);       // 4096x4096 bf16
  u16*   wT   = (u16*)(ws + 92274688);       // weights region
  u16*   wqkvT= wT;                          // [3072][1024]
  u16*   woT  = wT + (size_t)3072 * 1024;    // [1024][1024]
  u16*   w1T  = woT + (size_t)1024 * 1024;   // [4096][1024]
  u16*   w2T  = w1T + (size_t)4096 * 1024;   // [1024][4096]
  u16*   woutT= wT;                          // [32000][1024] (reuses region)

  embed_k<<<4096, 256, 0, stream>>>(tokens, tok_emb, pos_emb, x);

  for (int l = 0; l < 6; ++l){
    conv6_k<<<3072, 256, 0, stream>>>(Wq + (size_t)l*1048576, Wk + (size_t)l*1048576,
                                      Wv + (size_t)l*1048576, Wo + (size_t)l*1048576,
                                      W1 + (size_t)l*4194304, W2 + (size_t)l*4194304,
                                      wqkvT, woT, w1T, w2T);

    ln_k<<<4096, 256, 0, stream>>>(x, ln1g + l*1024, ln1b + l*1024, h);
    gemm_bt2<0><<<dim3(16,12), 512, 0, stream>>>(h, wqkvT, qkv, nullptr, 4096, 3072, 1024);
    attn_k<<<dim3(16,32), 256, 0, stream>>>(qkv, ctxb);
    gemm_bt<1><<<dim3(32,8), 256, 0, stream>>>(ctxb, woT, x, nullptr, 4096, 1024, 1024);
    ln_k<<<4096, 256, 0, stream>>>(x, ln2g + l*1024, ln2b + l*1024, h);
    gemm_bt2<2><<<dim3(16,16), 512, 0, stream>>>(h, w1T, h1, b1 + l*4096, 4096, 4096, 1024);
    gemm_bt<1><<<dim3(32,8), 256, 0, stream>>>(h1, w2T, x, b2 + l*1024, 4096, 1024, 4096);
  }

  ln_k<<<4096, 256, 0, stream>>>(x, lnfg, lnfb, h);
  conv_t<<<dim3(500,16), 256, 0, stream>>>(Wout, woutT, 1024, 32000);
  gemm_bt2<3><<<dim3(16,125), 512, 0, stream>>>(h, woutT, (float*)d_out, nullptr, 4096, 32000, 1024);
}